// Round 1
// baseline (3345.695 us; speedup 1.0000x reference)
//
#include <hip/hip_runtime.h>

typedef unsigned short u16;
typedef u16 u16x8 __attribute__((ext_vector_type(8)));
typedef short s16x8 __attribute__((ext_vector_type(8)));
typedef float f32x4 __attribute__((ext_vector_type(4)));

#define TT 4096   // B*S tokens
#define HH 2048   // hidden

__device__ __forceinline__ float bf2f(u16 u){ union{unsigned int i; float f;} v; v.i = ((unsigned int)u)<<16; return v.f; }
__device__ __forceinline__ u16 f2bf(float f){ union{float f; unsigned int i;} v; v.f = f; unsigned int r = v.i + 0x7fffu + ((v.i>>16)&1u); return (u16)(r>>16); }

// ---------------- transpose + fp32->bf16 convert: in [R][C] f32 -> out [C][ldo] bf16 (out[c*ldo+r]) ----------
__global__ __launch_bounds__(256) void tconv(const float* __restrict__ in, u16* __restrict__ out,
    int R, int C, int ldo, long inB, long outB){
  __shared__ float t[32][33];
  const float* inp = in + (long)blockIdx.z * inB;
  u16* outp = out + (long)blockIdx.z * outB;
  int c0 = blockIdx.x*32, r0 = blockIdx.y*32;
  int tx = threadIdx.x, ty = threadIdx.y;  // 32 x 8
  #pragma unroll
  for (int j=0;j<4;j++){
    int r = r0 + ty + j*8;
    t[ty+j*8][tx] = inp[(long)r*C + (c0+tx)];
  }
  __syncthreads();
  #pragma unroll
  for (int j=0;j<4;j++){
    int c = c0 + ty + j*8;
    outp[(long)c*ldo + (r0+tx)] = f2bf(t[tx][ty+j*8]);
  }
}

// ---------------- RMSNorm (fp32 in, bf16 out), one block per token ----------------
__global__ __launch_bounds__(256) void rmsnorm_k(const float* __restrict__ in, const float* __restrict__ w,
                                                 u16* __restrict__ out){
  long t = blockIdx.x;
  const float* row = in + t*HH;
  int tid = threadIdx.x;
  float x[8]; float ss = 0.f;
  #pragma unroll
  for (int i=0;i<8;i++){ x[i] = row[tid + i*256]; ss += x[i]*x[i]; }
  #pragma unroll
  for (int o=1;o<64;o<<=1) ss += __shfl_xor(ss, o, 64);
  __shared__ float sw[4];
  if ((tid&63)==0) sw[tid>>6] = ss;
  __syncthreads();
  ss = sw[0]+sw[1]+sw[2]+sw[3];
  float sc = rsqrtf(ss*(1.f/HH) + 1e-6f);
  #pragma unroll
  for (int i=0;i<8;i++){ int idx = tid+i*256; out[t*HH+idx] = f2bf(x[i]*sc*w[idx]); }
}

// ---------------- generic bf16 MFMA GEMM: C[M,N] = A[M,K] @ B^T  (B given as [N][K] bf16) ----------------
// 128x128 tile, BK=32, 4 waves (2x2 of 64x64), 16x16x32 bf16 MFMA.
// EPI 0: store bf16 C (row base=offsets[e] if GROUPED).  EPI 1: f32 (acc+Resid) -> Cf1 and Cf2.
// EPI 2: atomicAdd(Cf1[token*ldc+col], wlists[row]*acc)  (MoE down-proj scatter).
template<int EPI, bool GATHER, bool GROUPED>
__global__ __launch_bounds__(256) void gemm_bt(
    const u16* __restrict__ A, const u16* __restrict__ B,
    int K, int M_fixed,
    const int* __restrict__ counts, const int* __restrict__ offsets,
    const int* __restrict__ lists, const float* __restrict__ wlists,
    long strideB,
    u16* __restrict__ Cbf, int ldc,
    float* __restrict__ Cf1, float* __restrict__ Cf2,
    const float* __restrict__ Resid)
{
  int e = GROUPED ? blockIdx.z : 0;
  int cnt = GROUPED ? counts[e] : M_fixed;
  int m0 = blockIdx.y * 128;
  if (m0 >= cnt) return;
  int n0 = blockIdx.x * 128;
  int base = GROUPED ? offsets[e] : 0;
  const u16* B2 = B + (long)e * strideB;

  __shared__ u16 lA[128*40];
  __shared__ u16 lB[128*40];

  int tid = threadIdx.x;
  int wave = tid>>6, lane = tid&63;
  int wm = (wave>>1)*64, wn = (wave&1)*64;
  int quad = lane>>4, l16 = lane&15;

  // staging addresses: thread handles rows (tid>>2) and (tid>>2)+64, k-chunk (tid&3)*8
  int kA = (tid&3)*8;
  int r0a = m0 + (tid>>2), r1a = r0a + 64;
  if (r0a >= cnt) r0a = cnt-1;
  if (r1a >= cnt) r1a = cnt-1;
  long ga0, ga1;
  if constexpr (GATHER){ ga0 = (long)lists[e*4096 + r0a]*K; ga1 = (long)lists[e*4096 + r1a]*K; }
  else if constexpr (GROUPED){ ga0 = (long)(base + r0a)*K; ga1 = (long)(base + r1a)*K; }
  else { ga0 = (long)r0a*K; ga1 = (long)r1a*K; }
  ga0 += kA; ga1 += kA;
  long gb0 = (long)(n0 + (tid>>2))*K + kA;
  long gb1 = gb0 + 64L*K;
  int lr = (tid>>2)*40 + kA;

  f32x4 zero = {0.f,0.f,0.f,0.f};
  f32x4 acc[4][4];
  #pragma unroll
  for (int i=0;i<4;i++)
    #pragma unroll
    for (int j=0;j<4;j++) acc[i][j] = zero;

  for (int kt=0; kt<K; kt+=32){
    *(u16x8*)(&lA[lr])        = *(const u16x8*)(A + ga0 + kt);
    *(u16x8*)(&lA[lr + 64*40])= *(const u16x8*)(A + ga1 + kt);
    *(u16x8*)(&lB[lr])        = *(const u16x8*)(B2 + gb0 + kt);
    *(u16x8*)(&lB[lr + 64*40])= *(const u16x8*)(B2 + gb1 + kt);
    __syncthreads();
    s16x8 af[4], bfr[4];
    #pragma unroll
    for (int i=0;i<4;i++){
      af[i]  = *(const s16x8*)(&lA[(wm + i*16 + l16)*40 + quad*8]);
      bfr[i] = *(const s16x8*)(&lB[(wn + i*16 + l16)*40 + quad*8]);
    }
    #pragma unroll
    for (int i=0;i<4;i++)
      #pragma unroll
      for (int j=0;j<4;j++)
        acc[i][j] = __builtin_amdgcn_mfma_f32_16x16x32_bf16(af[i], bfr[j], acc[i][j], 0,0,0);
    __syncthreads();
  }

  #pragma unroll
  for (int i=0;i<4;i++){
    #pragma unroll
    for (int j=0;j<4;j++){
      #pragma unroll
      for (int rr=0; rr<4; rr++){
        int row = m0 + wm + i*16 + quad*4 + rr;
        int col = n0 + wn + j*16 + l16;
        float v = acc[i][j][rr];
        if constexpr (EPI==0){
          if (row < cnt) Cbf[(long)(base+row)*ldc + col] = f2bf(v);
        } else if constexpr (EPI==1){
          long idx = (long)row*ldc + col;
          float o = v + Resid[idx];
          Cf1[idx] = o; Cf2[idx] = o;
        } else {
          if (row < cnt){
            int tk = lists[e*4096 + row];
            float wgt = wlists[e*4096 + row];
            atomicAdd(&Cf1[(long)tk*ldc + col], wgt*v);
          }
        }
      }
    }
  }
}

// ---------------- RoPE in-place on q (16 heads) and k (4 heads) parts of qkv_bf [T][3072] ----------------
__global__ __launch_bounds__(256) void rope_k(u16* __restrict__ qkv, const float* __restrict__ cosb,
                                              const float* __restrict__ sinb){
  long t = blockIdx.x;
  for (int p = threadIdx.x; p < 1280; p += 256){
    int head = p>>6, d = p&63;
    long base = t*3072 + (head<16 ? head*128 : 2048 + (head-16)*128);
    float c1 = cosb[t*128+d],    s1 = sinb[t*128+d];
    float c2 = cosb[t*128+d+64], s2 = sinb[t*128+d+64];
    float x1 = bf2f(qkv[base+d]), x2 = bf2f(qkv[base+d+64]);
    qkv[base+d]    = f2bf(x1*c1 - x2*s1);
    qkv[base+d+64] = f2bf(x2*c2 + x1*s2);
  }
}

// ---------------- flash attention (full, non-causal), GQA 16q/4kv heads, D=128 ----------------
// block = 256 threads: 32 queries x 8 d-slots (16 dims each). Key tiles of 32.
__global__ __launch_bounds__(256) void attn_k(const u16* __restrict__ qkv, u16* __restrict__ out){
  __shared__ float lK[32][128];
  __shared__ float lV[32][128];
  int qt = blockIdx.x, h = blockIdx.y, b = blockIdx.z;
  int g = h>>2;
  int tid = threadIdx.x;
  int ql = tid>>3, dsl = (tid&7)*16;
  long tq = (long)b*2048 + qt*32 + ql;
  const float scale = 0.08838834764831845f;  // 1/sqrt(128)
  float qreg[16];
  #pragma unroll
  for (int i=0;i<16;i++) qreg[i] = bf2f(qkv[tq*3072 + h*128 + dsl + i]) * scale;
  float m = -1e30f, l = 0.f;
  float acc[16];
  #pragma unroll
  for (int i=0;i<16;i++) acc[i] = 0.f;

  for (int kt=0; kt<64; ++kt){
    #pragma unroll
    for (int c = tid; c < 512; c += 256){
      int key = c>>4, off = (c&15)*8;
      long tk = (long)b*2048 + kt*32 + key;
      const u16* kp = qkv + tk*3072 + 2048 + g*128 + off;
      u16x8 k8 = *(const u16x8*)kp;
      u16x8 v8 = *(const u16x8*)(kp + 512);
      #pragma unroll
      for (int j=0;j<8;j++){ lK[key][off+j] = bf2f(k8[j]); lV[key][off+j] = bf2f(v8[j]); }
    }
    __syncthreads();
    float s[32];
    #pragma unroll
    for (int k=0;k<32;k++){
      float p = 0.f;
      const float* kr = &lK[k][dsl];
      #pragma unroll
      for (int i=0;i<16;i++) p += qreg[i]*kr[i];
      p += __shfl_xor(p,1,64); p += __shfl_xor(p,2,64); p += __shfl_xor(p,4,64);
      s[k] = p;
    }
    float mn = m;
    #pragma unroll
    for (int k=0;k<32;k++) mn = fmaxf(mn, s[k]);
    float alpha = __expf(m - mn);
    float psum = 0.f;
    #pragma unroll
    for (int k=0;k<32;k++){ s[k] = __expf(s[k]-mn); psum += s[k]; }
    l = l*alpha + psum; m = mn;
    #pragma unroll
    for (int i=0;i<16;i++) acc[i] *= alpha;
    #pragma unroll
    for (int k=0;k<32;k++){
      float pk = s[k];
      const float* vr = &lV[k][dsl];
      #pragma unroll
      for (int i=0;i<16;i++) acc[i] += pk*vr[i];
    }
    __syncthreads();
  }
  float inv = 1.f/l;
  long ot = tq*2048 + h*128 + dsl;
  #pragma unroll
  for (int i=0;i<16;i++) out[ot+i] = f2bf(acc[i]*inv);
}

// ---------------- router: fused rmsnorm + logits(fp32) + softmax + top2 + routing lists ----------------
__global__ __launch_bounds__(256) void router_k(const float* __restrict__ h2, const float* __restrict__ w2,
    const float* __restrict__ rw, int* counts, int* lists, float* wlists){
  long t = blockIdx.x;
  const float* row = h2 + t*HH;
  int tid = threadIdx.x;
  float x[8]; float ss = 0.f;
  #pragma unroll
  for (int i=0;i<8;i++){ int idx = tid + i*256; x[i]=row[idx]; ss += x[i]*x[i]; }
  #pragma unroll
  for (int o=1;o<64;o<<=1) ss += __shfl_xor(ss,o,64);
  __shared__ float ssw[4];
  int wave = tid>>6, lane = tid&63;
  if (lane==0) ssw[wave]=ss;
  __syncthreads();
  ss = ssw[0]+ssw[1]+ssw[2]+ssw[3];
  float sc = rsqrtf(ss*(1.f/HH) + 1e-6f);
  float part[8] = {0,0,0,0,0,0,0,0};
  #pragma unroll
  for (int i=0;i<8;i++){
    int idx = tid + i*256;
    float xn = x[i]*sc*w2[idx];
    const float* r8 = rw + (long)idx*8;
    #pragma unroll
    for (int e2=0;e2<8;e2++) part[e2] += xn*r8[e2];
  }
  #pragma unroll
  for (int e2=0;e2<8;e2++)
    #pragma unroll
    for (int o=1;o<64;o<<=1) part[e2] += __shfl_xor(part[e2],o,64);
  __shared__ float pw[4][8];
  if (lane==0){
    #pragma unroll
    for (int e2=0;e2<8;e2++) pw[wave][e2]=part[e2];
  }
  __syncthreads();
  if (tid==0){
    float lg[8];
    #pragma unroll
    for (int e2=0;e2<8;e2++) lg[e2]=pw[0][e2]+pw[1][e2]+pw[2][e2]+pw[3][e2];
    float mx = lg[0];
    #pragma unroll
    for (int e2=1;e2<8;e2++) mx = fmaxf(mx, lg[e2]);
    float pz[8];
    #pragma unroll
    for (int e2=0;e2<8;e2++) pz[e2] = __expf(lg[e2]-mx);
    int i1 = 0;
    #pragma unroll
    for (int e2=1;e2<8;e2++) if (pz[e2] > pz[i1]) i1 = e2;
    int i2 = (i1==0) ? 1 : 0;
    #pragma unroll
    for (int e2=0;e2<8;e2++) if (e2!=i1 && pz[e2] > pz[i2]) i2 = e2;
    float v1 = pz[i1], v2 = pz[i2];
    float inv = 1.f/(v1+v2);
    int p1 = atomicAdd(&counts[i1],1);
    lists[i1*4096+p1] = (int)t; wlists[i1*4096+p1] = v1*inv;
    int p2 = atomicAdd(&counts[i2],1);
    lists[i2*4096+p2] = (int)t; wlists[i2*4096+p2] = v2*inv;
  }
}

__global__ void zero8(int* p){ if (threadIdx.x < 8) p[threadIdx.x] = 0; }
__global__ void prefix8(const int* __restrict__ counts, int* __restrict__ offs){
  if (threadIdx.x==0){ int o=0; for (int e=0;e<8;e++){ offs[e]=o; o+=counts[e]; } }
}

// ---------------- silu(g)*u elementwise: guraw [8192][2816] -> gu [8192][1408] ----------------
__global__ __launch_bounds__(256) void silu_k(const u16* __restrict__ graw, u16* __restrict__ gu){
  long row = blockIdx.x;
  const u16* gr = graw + row*2816;
  u16* o = gu + row*1408;
  for (int i = threadIdx.x; i < 1408; i += 256){
    float g = bf2f(gr[i]);
    float u = bf2f(gr[1408+i]);
    float s = g / (1.f + __expf(-g));
    o[i] = f2bf(s*u);
  }
}

// ---------------- workspace layout (bytes), total 268,697,664 required ----------------
static constexpr long OFF_WQKV  = 0;                      // [3072][2048] bf16 (wq|wk|wv transposed)
static constexpr long OFF_WO    = 12582912;               // [2048][2048] bf16
static constexpr long OFF_GUW   = 20971520;               // [8][2816][2048] bf16 (gate|up transposed)
static constexpr long OFF_DW    = 113246208;              // [8][2048][1408] bf16
static constexpr long ARENA     = 159383552;
static constexpr long OFF_XBF   = ARENA;                  // [4096][2048] bf16
static constexpr long OFF_QKV   = ARENA + 16777216;       // [4096][3072] bf16
static constexpr long OFF_ATT   = ARENA + 41943040;       // [4096][2048] bf16
static constexpr long OFF_GURAW = ARENA;                  // [8192][2816] bf16 (aliases x/qkv/att, dead by then)
static constexpr long OFF_H2    = 218103808;              // [4096][2048] f32
static constexpr long OFF_GU    = 218103808;              // [8192(+pad)][1408] bf16 (aliases h2, dead by then)
static constexpr long OFF_X2    = 251658240;              // [4096][2048] bf16
static constexpr long OFF_CNT   = 268435456;              // 8 int
static constexpr long OFF_OFFS  = 268435488;              // 8 int
static constexpr long OFF_LIST  = 268435520;              // 8*4096 int
static constexpr long OFF_WL    = 268566592;              // 8*4096 f32

extern "C" void kernel_launch(void* const* d_in, const int* in_sizes, int n_in,
                              void* d_out, int out_size, void* d_ws, size_t ws_size,
                              hipStream_t stream) {
  const float* hs   = (const float*)d_in[0];
  const float* cosb = (const float*)d_in[1];
  const float* sinb = (const float*)d_in[2];
  const float* wq   = (const float*)d_in[3];
  const float* wk   = (const float*)d_in[4];
  const float* wv   = (const float*)d_in[5];
  const float* wo   = (const float*)d_in[6];
  const float* ln1  = (const float*)d_in[7];
  const float* ln2  = (const float*)d_in[8];
  const float* rw   = (const float*)d_in[9];
  const float* gw   = (const float*)d_in[10];
  const float* uw   = (const float*)d_in[11];
  const float* dw   = (const float*)d_in[12];
  float* out = (float*)d_out;
  char* ws = (char*)d_ws;

  u16* wqkv_bt = (u16*)(ws + OFF_WQKV);
  u16* wo_bt   = (u16*)(ws + OFF_WO);
  u16* guw_bt  = (u16*)(ws + OFF_GUW);
  u16* dw_bt   = (u16*)(ws + OFF_DW);
  u16* x_bf    = (u16*)(ws + OFF_XBF);
  u16* qkv_bf  = (u16*)(ws + OFF_QKV);
  u16* att_bf  = (u16*)(ws + OFF_ATT);
  u16* guraw   = (u16*)(ws + OFF_GURAW);
  float* h2    = (float*)(ws + OFF_H2);
  u16* gu      = (u16*)(ws + OFF_GU);
  u16* x2_bf   = (u16*)(ws + OFF_X2);
  int* counts  = (int*)(ws + OFF_CNT);
  int* offs    = (int*)(ws + OFF_OFFS);
  int* lists   = (int*)(ws + OFF_LIST);
  float* wlists= (float*)(ws + OFF_WL);

  dim3 tb(32,8);
  // weight transposes + bf16 conversion
  tconv<<<dim3(64,64,1),tb,0,stream>>>(wq, wqkv_bt,                2048,2048,2048, 0,0);
  tconv<<<dim3(16,64,1),tb,0,stream>>>(wk, wqkv_bt + 2048L*2048,   2048, 512,2048, 0,0);
  tconv<<<dim3(16,64,1),tb,0,stream>>>(wv, wqkv_bt + 2560L*2048,   2048, 512,2048, 0,0);
  tconv<<<dim3(64,64,1),tb,0,stream>>>(wo, wo_bt,                  2048,2048,2048, 0,0);
  tconv<<<dim3(44,64,8),tb,0,stream>>>(gw, guw_bt,                 2048,1408,2048, 2048L*1408, 2816L*2048);
  tconv<<<dim3(44,64,8),tb,0,stream>>>(uw, guw_bt + 1408L*2048,    2048,1408,2048, 2048L*1408, 2816L*2048);
  tconv<<<dim3(64,44,8),tb,0,stream>>>(dw, dw_bt,                  1408,2048,1408, 1408L*2048, 2048L*1408);

  // rmsnorm1 -> x_bf
  rmsnorm_k<<<TT,256,0,stream>>>(hs, ln1, x_bf);

  // qkv = x @ [wq|wk|wv]  -> bf16 [4096][3072]
  gemm_bt<0,false,false><<<dim3(24,32,1),256,0,stream>>>(x_bf, wqkv_bt, 2048, 4096,
      nullptr,nullptr,nullptr,nullptr, 0, qkv_bf, 3072, nullptr,nullptr,nullptr);

  // rope on q,k
  rope_k<<<TT,256,0,stream>>>(qkv_bf, cosb, sinb);

  // attention -> att_bf [4096][2048]
  attn_k<<<dim3(64,16,2),256,0,stream>>>(qkv_bf, att_bf);

  // h2 = hs + att @ wo  (also prefill d_out with h2)
  gemm_bt<1,false,false><<<dim3(16,32,1),256,0,stream>>>(att_bf, wo_bt, 2048, 4096,
      nullptr,nullptr,nullptr,nullptr, 0, nullptr, 2048, h2, out, hs);

  // rmsnorm2 -> x2_bf ; router -> lists/weights
  rmsnorm_k<<<TT,256,0,stream>>>(h2, ln2, x2_bf);
  zero8<<<1,64,0,stream>>>(counts);
  router_k<<<TT,256,0,stream>>>(h2, ln2, rw, counts, lists, wlists);
  prefix8<<<1,64,0,stream>>>(counts, offs);

  // grouped gate/up GEMM (gathered rows): guraw[offset[e]+r][0:2816]
  gemm_bt<0,true,true><<<dim3(22,32,8),256,0,stream>>>(x2_bf, guw_bt, 2048, 0,
      counts, offs, lists, wlists, 2816L*2048, guraw, 2816, nullptr,nullptr,nullptr);

  // silu(g)*u -> gu [8192][1408]
  silu_k<<<8192,256,0,stream>>>(guraw, gu);

  // grouped down GEMM, scatter-add into out with combine weights
  gemm_bt<2,false,true><<<dim3(16,32,8),256,0,stream>>>(gu, dw_bt, 1408, 0,
      counts, offs, lists, wlists, 2048L*1408, nullptr, 2048, out, nullptr, nullptr);

  (void)in_sizes; (void)n_in; (void)out_size; (void)ws_size;
}

// Round 2
// 1154.626 us; speedup vs baseline: 2.8976x; 2.8976x over previous
//
#include <hip/hip_runtime.h>

typedef unsigned short u16;
typedef u16 u16x8 __attribute__((ext_vector_type(8)));
typedef short s16x8 __attribute__((ext_vector_type(8)));
typedef float f32x4 __attribute__((ext_vector_type(4)));

#define TT 4096   // B*S tokens
#define HH 2048   // hidden

__device__ __forceinline__ float bf2f(u16 u){ union{unsigned int i; float f;} v; v.i = ((unsigned int)u)<<16; return v.f; }
__device__ __forceinline__ u16 f2bf(float f){ union{float f; unsigned int i;} v; v.f = f; unsigned int r = v.i + 0x7fffu + ((v.i>>16)&1u); return (u16)(r>>16); }

// ---------------- transpose + fp32->bf16 convert: in [R][C] f32 -> out [C][ldo] bf16 (out[c*ldo+r]) ----------
__global__ __launch_bounds__(256) void tconv(const float* __restrict__ in, u16* __restrict__ out,
    int R, int C, int ldo, long inB, long outB){
  __shared__ float t[32][33];
  const float* inp = in + (long)blockIdx.z * inB;
  u16* outp = out + (long)blockIdx.z * outB;
  int c0 = blockIdx.x*32, r0 = blockIdx.y*32;
  int tx = threadIdx.x, ty = threadIdx.y;  // 32 x 8
  #pragma unroll
  for (int j=0;j<4;j++){
    int r = r0 + ty + j*8;
    t[ty+j*8][tx] = inp[(long)r*C + (c0+tx)];
  }
  __syncthreads();
  #pragma unroll
  for (int j=0;j<4;j++){
    int c = c0 + ty + j*8;
    outp[(long)c*ldo + (r0+tx)] = f2bf(t[tx][ty+j*8]);
  }
}

// ---------------- bf16 transpose of V slice: qkv[t][2560+g*128+d] -> vt[(b*4+g)][d][s] ----------------
__global__ __launch_bounds__(256) void vtrans(const u16* __restrict__ qkv, u16* __restrict__ vt){
  __shared__ u16 t[32][34];
  int bg = blockIdx.z; int b = bg>>2, g = bg&3;
  int s0 = blockIdx.x*32, d0 = blockIdx.y*32;
  int tx = threadIdx.x, ty = threadIdx.y;  // 32 x 8
  #pragma unroll
  for (int j=0;j<4;j++){
    t[ty+j*8][tx] = qkv[(long)(b*2048 + s0+ty+j*8)*3072 + 2560 + g*128 + d0+tx];
  }
  __syncthreads();
  #pragma unroll
  for (int j=0;j<4;j++){
    vt[((long)bg*128 + d0+ty+j*8)*2048 + s0+tx] = t[tx][ty+j*8];
  }
}

// ---------------- RMSNorm (fp32 in, bf16 out), one block per token ----------------
__global__ __launch_bounds__(256) void rmsnorm_k(const float* __restrict__ in, const float* __restrict__ w,
                                                 u16* __restrict__ out){
  long t = blockIdx.x;
  const float* row = in + t*HH;
  int tid = threadIdx.x;
  float x[8]; float ss = 0.f;
  #pragma unroll
  for (int i=0;i<8;i++){ x[i] = row[tid + i*256]; ss += x[i]*x[i]; }
  #pragma unroll
  for (int o=1;o<64;o<<=1) ss += __shfl_xor(ss, o, 64);
  __shared__ float sw[4];
  if ((tid&63)==0) sw[tid>>6] = ss;
  __syncthreads();
  ss = sw[0]+sw[1]+sw[2]+sw[3];
  float sc = rsqrtf(ss*(1.f/HH) + 1e-6f);
  #pragma unroll
  for (int i=0;i<8;i++){ int idx = tid+i*256; out[t*HH+idx] = f2bf(x[i]*sc*w[idx]); }
}

// ---------------- generic bf16 MFMA GEMM: C[M,N] = A[M,K] @ B^T  (B given as [N][K] bf16) ----------------
template<int EPI, bool GATHER, bool GROUPED>
__global__ __launch_bounds__(256) void gemm_bt(
    const u16* __restrict__ A, const u16* __restrict__ B,
    int K, int M_fixed,
    const int* __restrict__ counts, const int* __restrict__ offsets,
    const int* __restrict__ lists, const float* __restrict__ wlists,
    long strideB,
    u16* __restrict__ Cbf, int ldc,
    float* __restrict__ Cf1, float* __restrict__ Cf2,
    const float* __restrict__ Resid)
{
  int e = GROUPED ? blockIdx.z : 0;
  int cnt = GROUPED ? counts[e] : M_fixed;
  int m0 = blockIdx.y * 128;
  if (m0 >= cnt) return;
  int n0 = blockIdx.x * 128;
  int base = GROUPED ? offsets[e] : 0;
  const u16* B2 = B + (long)e * strideB;

  __shared__ u16 lA[128*40];
  __shared__ u16 lB[128*40];

  int tid = threadIdx.x;
  int wave = tid>>6, lane = tid&63;
  int wm = (wave>>1)*64, wn = (wave&1)*64;
  int quad = lane>>4, l16 = lane&15;

  int kA = (tid&3)*8;
  int r0a = m0 + (tid>>2), r1a = r0a + 64;
  if (r0a >= cnt) r0a = cnt-1;
  if (r1a >= cnt) r1a = cnt-1;
  long ga0, ga1;
  if constexpr (GATHER){ ga0 = (long)lists[e*4096 + r0a]*K; ga1 = (long)lists[e*4096 + r1a]*K; }
  else if constexpr (GROUPED){ ga0 = (long)(base + r0a)*K; ga1 = (long)(base + r1a)*K; }
  else { ga0 = (long)r0a*K; ga1 = (long)r1a*K; }
  ga0 += kA; ga1 += kA;
  long gb0 = (long)(n0 + (tid>>2))*K + kA;
  long gb1 = gb0 + 64L*K;
  int lr = (tid>>2)*40 + kA;

  f32x4 zero = {0.f,0.f,0.f,0.f};
  f32x4 acc[4][4];
  #pragma unroll
  for (int i=0;i<4;i++)
    #pragma unroll
    for (int j=0;j<4;j++) acc[i][j] = zero;

  for (int kt=0; kt<K; kt+=32){
    *(u16x8*)(&lA[lr])        = *(const u16x8*)(A + ga0 + kt);
    *(u16x8*)(&lA[lr + 64*40])= *(const u16x8*)(A + ga1 + kt);
    *(u16x8*)(&lB[lr])        = *(const u16x8*)(B2 + gb0 + kt);
    *(u16x8*)(&lB[lr + 64*40])= *(const u16x8*)(B2 + gb1 + kt);
    __syncthreads();
    s16x8 af[4], bfr[4];
    #pragma unroll
    for (int i=0;i<4;i++){
      af[i]  = *(const s16x8*)(&lA[(wm + i*16 + l16)*40 + quad*8]);
      bfr[i] = *(const s16x8*)(&lB[(wn + i*16 + l16)*40 + quad*8]);
    }
    #pragma unroll
    for (int i=0;i<4;i++)
      #pragma unroll
      for (int j=0;j<4;j++)
        acc[i][j] = __builtin_amdgcn_mfma_f32_16x16x32_bf16(af[i], bfr[j], acc[i][j], 0,0,0);
    __syncthreads();
  }

  #pragma unroll
  for (int i=0;i<4;i++){
    #pragma unroll
    for (int j=0;j<4;j++){
      #pragma unroll
      for (int rr=0; rr<4; rr++){
        int row = m0 + wm + i*16 + quad*4 + rr;
        int col = n0 + wn + j*16 + l16;
        float v = acc[i][j][rr];
        if constexpr (EPI==0){
          if (row < cnt) Cbf[(long)(base+row)*ldc + col] = f2bf(v);
        } else if constexpr (EPI==1){
          long idx = (long)row*ldc + col;
          float o = v + Resid[idx];
          Cf1[idx] = o; Cf2[idx] = o;
        } else {
          if (row < cnt){
            int tk = lists[e*4096 + row];
            float wgt = wlists[e*4096 + row];
            atomicAdd(&Cf1[(long)tk*ldc + col], wgt*v);
          }
        }
      }
    }
  }
}

// ---------------- RoPE in-place on q (16 heads) and k (4 heads) parts of qkv_bf [T][3072] ----------------
__global__ __launch_bounds__(256) void rope_k(u16* __restrict__ qkv, const float* __restrict__ cosb,
                                              const float* __restrict__ sinb){
  long t = blockIdx.x;
  for (int p = threadIdx.x; p < 1280; p += 256){
    int head = p>>6, d = p&63;
    long base = t*3072 + (head<16 ? head*128 : 2048 + (head-16)*128);
    float c1 = cosb[t*128+d],    s1 = sinb[t*128+d];
    float c2 = cosb[t*128+d+64], s2 = sinb[t*128+d+64];
    float x1 = bf2f(qkv[base+d]), x2 = bf2f(qkv[base+d+64]);
    qkv[base+d]    = f2bf(x1*c1 - x2*s1);
    qkv[base+d+64] = f2bf(x2*c2 + x1*s2);
  }
}

// ---------------- MFMA flash attention (full, non-causal), GQA 16q/4kv, D=128 ----------------
// Block: 128 q-rows for one (b,h); 4 waves x 32 rows. K-tile = 64.
__global__ __launch_bounds__(256,2) void attn_k(const u16* __restrict__ qkv, const u16* __restrict__ vt,
                                                u16* __restrict__ out){
  __shared__ u16 lK [64*136];   // [key][d], ld=136
  __shared__ u16 lVt[128*72];   // [d][key], ld=72
  __shared__ u16 lP [4*32*72];  // per-wave [qrow][key], ld=72
  int qt = blockIdx.x, h = blockIdx.y, b = blockIdx.z;
  int g = h>>2;
  int tid = threadIdx.x, wave = tid>>6, lane = tid&63;
  int quad = lane>>4, l16 = lane&15;
  long qbase = (long)b*2048 + qt*128;
  const float c = 0.08838834764831845f * 1.4426950408889634f;  // scale * log2(e)

  // Q a-frags resident: qf[i][kk], lane m=l16 (row i*16+l16), k = kk*32+quad*8..+7
  s16x8 qf[2][4];
  #pragma unroll
  for (int i=0;i<2;i++){
    long tok = qbase + wave*32 + i*16 + l16;
    #pragma unroll
    for (int kk=0;kk<4;kk++)
      qf[i][kk] = *(const s16x8*)(qkv + tok*3072 + h*128 + kk*32 + quad*8);
  }

  f32x4 O[2][8];
  #pragma unroll
  for (int i=0;i<2;i++)
    #pragma unroll
    for (int f=0;f<8;f++) O[i][f] = (f32x4){0.f,0.f,0.f,0.f};
  float mS[2][4], lS[2][4];
  #pragma unroll
  for (int i=0;i<2;i++)
    #pragma unroll
    for (int rr=0;rr<4;rr++){ mS[i][rr] = -1e30f; lS[i][rr] = 0.f; }

  const u16* kbase  = qkv + (long)b*2048*3072 + 2048 + g*128;
  const u16* vtbase = vt + ((long)(b*4+g))*128*2048;
  int koct = tid&15, krow = tid>>4;   // K staging: 16 octs x 16 rows (x4)
  int voct = tid&7,  vrow = tid>>3;   // Vt staging: 8 octs x 32 rows (x4)
  u16* lPw = lP + wave*32*72;

  for (int kt=0; kt<2048; kt+=64){
    __syncthreads();
    #pragma unroll
    for (int j2=0;j2<4;j2++){
      int r = krow + j2*16;
      *(u16x8*)(lK + r*136 + koct*8) = *(const u16x8*)(kbase + (long)(kt+r)*3072 + koct*8);
    }
    #pragma unroll
    for (int j2=0;j2<4;j2++){
      int d = vrow + j2*32;
      *(u16x8*)(lVt + d*72 + voct*8) = *(const u16x8*)(vtbase + (long)d*2048 + kt + voct*8);
    }
    __syncthreads();

    // S = Q @ K^T  (C layout: row=q=quad*4+rr, col=key=l16 within frag j)
    f32x4 S[2][4];
    #pragma unroll
    for (int i=0;i<2;i++)
      #pragma unroll
      for (int j=0;j<4;j++) S[i][j] = (f32x4){0.f,0.f,0.f,0.f};
    #pragma unroll
    for (int kk=0;kk<4;kk++){
      s16x8 bk[4];
      #pragma unroll
      for (int j=0;j<4;j++)
        bk[j] = *(const s16x8*)(lK + (j*16+l16)*136 + kk*32 + quad*8);
      #pragma unroll
      for (int i=0;i<2;i++)
        #pragma unroll
        for (int j=0;j<4;j++)
          S[i][j] = __builtin_amdgcn_mfma_f32_16x16x32_bf16(qf[i][kk], bk[j], S[i][j], 0,0,0);
    }

    // online softmax + P write
    #pragma unroll
    for (int i=0;i<2;i++){
      float al[4];
      #pragma unroll
      for (int rr=0;rr<4;rr++){
        float v = fmaxf(fmaxf(S[i][0][rr],S[i][1][rr]), fmaxf(S[i][2][rr],S[i][3][rr]));
        v = fmaxf(v, __shfl_xor(v,1,64));
        v = fmaxf(v, __shfl_xor(v,2,64));
        v = fmaxf(v, __shfl_xor(v,4,64));
        v = fmaxf(v, __shfl_xor(v,8,64));
        float mn = fmaxf(v, mS[i][rr]);
        al[rr] = exp2f((mS[i][rr]-mn)*c);
        mS[i][rr] = mn;
        float rs = 0.f;
        #pragma unroll
        for (int j=0;j<4;j++){
          float p = exp2f((S[i][j][rr]-mn)*c);
          S[i][j][rr] = p; rs += p;
        }
        rs += __shfl_xor(rs,1,64);
        rs += __shfl_xor(rs,2,64);
        rs += __shfl_xor(rs,4,64);
        rs += __shfl_xor(rs,8,64);
        lS[i][rr] = lS[i][rr]*al[rr] + rs;
      }
      #pragma unroll
      for (int j=0;j<4;j++)
        #pragma unroll
        for (int rr=0;rr<4;rr++)
          lPw[(i*16 + quad*4 + rr)*72 + j*16 + l16] = f2bf(S[i][j][rr]);
      #pragma unroll
      for (int f=0;f<8;f++)
        #pragma unroll
        for (int rr=0;rr<4;rr++) O[i][f][rr] *= al[rr];
    }

    // O += P @ V   (P a-frags from LDS round-trip; V b-frags from transposed lVt)
    #pragma unroll
    for (int kk=0;kk<2;kk++){
      s16x8 ap[2];
      #pragma unroll
      for (int i=0;i<2;i++)
        ap[i] = *(const s16x8*)(lPw + (i*16+l16)*72 + kk*32 + quad*8);
      #pragma unroll
      for (int f=0;f<8;f++){
        s16x8 bv = *(const s16x8*)(lVt + (f*16+l16)*72 + kk*32 + quad*8);
        O[0][f] = __builtin_amdgcn_mfma_f32_16x16x32_bf16(ap[0], bv, O[0][f], 0,0,0);
        O[1][f] = __builtin_amdgcn_mfma_f32_16x16x32_bf16(ap[1], bv, O[1][f], 0,0,0);
      }
    }
  }

  #pragma unroll
  for (int i=0;i<2;i++){
    float inv[4];
    #pragma unroll
    for (int rr=0;rr<4;rr++) inv[rr] = 1.f/lS[i][rr];
    #pragma unroll
    for (int f=0;f<8;f++)
      #pragma unroll
      for (int rr=0;rr<4;rr++){
        long tok = qbase + wave*32 + i*16 + quad*4 + rr;
        out[tok*2048 + h*128 + f*16 + l16] = f2bf(O[i][f][rr]*inv[rr]);
      }
  }
}

// ---------------- router: fused rmsnorm + logits(fp32) + softmax + top2 + routing lists ----------------
__global__ __launch_bounds__(256) void router_k(const float* __restrict__ h2, const float* __restrict__ w2,
    const float* __restrict__ rw, int* counts, int* lists, float* wlists){
  long t = blockIdx.x;
  const float* row = h2 + t*HH;
  int tid = threadIdx.x;
  float x[8]; float ss = 0.f;
  #pragma unroll
  for (int i=0;i<8;i++){ int idx = tid + i*256; x[i]=row[idx]; ss += x[i]*x[i]; }
  #pragma unroll
  for (int o=1;o<64;o<<=1) ss += __shfl_xor(ss,o,64);
  __shared__ float ssw[4];
  int wave = tid>>6, lane = tid&63;
  if (lane==0) ssw[wave]=ss;
  __syncthreads();
  ss = ssw[0]+ssw[1]+ssw[2]+ssw[3];
  float sc = rsqrtf(ss*(1.f/HH) + 1e-6f);
  float part[8] = {0,0,0,0,0,0,0,0};
  #pragma unroll
  for (int i=0;i<8;i++){
    int idx = tid + i*256;
    float xn = x[i]*sc*w2[idx];
    const float* r8 = rw + (long)idx*8;
    #pragma unroll
    for (int e2=0;e2<8;e2++) part[e2] += xn*r8[e2];
  }
  #pragma unroll
  for (int e2=0;e2<8;e2++)
    #pragma unroll
    for (int o=1;o<64;o<<=1) part[e2] += __shfl_xor(part[e2],o,64);
  __shared__ float pw[4][8];
  if (lane==0){
    #pragma unroll
    for (int e2=0;e2<8;e2++) pw[wave][e2]=part[e2];
  }
  __syncthreads();
  if (tid==0){
    float lg[8];
    #pragma unroll
    for (int e2=0;e2<8;e2++) lg[e2]=pw[0][e2]+pw[1][e2]+pw[2][e2]+pw[3][e2];
    float mx = lg[0];
    #pragma unroll
    for (int e2=1;e2<8;e2++) mx = fmaxf(mx, lg[e2]);
    float pz[8];
    #pragma unroll
    for (int e2=0;e2<8;e2++) pz[e2] = __expf(lg[e2]-mx);
    int i1 = 0;
    #pragma unroll
    for (int e2=1;e2<8;e2++) if (pz[e2] > pz[i1]) i1 = e2;
    int i2 = (i1==0) ? 1 : 0;
    #pragma unroll
    for (int e2=0;e2<8;e2++) if (e2!=i1 && pz[e2] > pz[i2]) i2 = e2;
    float v1 = pz[i1], v2 = pz[i2];
    float inv = 1.f/(v1+v2);
    int p1 = atomicAdd(&counts[i1],1);
    lists[i1*4096+p1] = (int)t; wlists[i1*4096+p1] = v1*inv;
    int p2 = atomicAdd(&counts[i2],1);
    lists[i2*4096+p2] = (int)t; wlists[i2*4096+p2] = v2*inv;
  }
}

__global__ void zero8(int* p){ if (threadIdx.x < 8) p[threadIdx.x] = 0; }
__global__ void prefix8(const int* __restrict__ counts, int* __restrict__ offs){
  if (threadIdx.x==0){ int o=0; for (int e=0;e<8;e++){ offs[e]=o; o+=counts[e]; } }
}

// ---------------- silu(g)*u elementwise: guraw [8192][2816] -> gu [8192][1408] ----------------
__global__ __launch_bounds__(256) void silu_k(const u16* __restrict__ graw, u16* __restrict__ gu){
  long row = blockIdx.x;
  const u16* gr = graw + row*2816;
  u16* o = gu + row*1408;
  for (int i = threadIdx.x; i < 1408; i += 256){
    float g = bf2f(gr[i]);
    float u = bf2f(gr[1408+i]);
    float s = g / (1.f + __expf(-g));
    o[i] = f2bf(s*u);
  }
}

// ---------------- workspace layout (bytes) ----------------
static constexpr long OFF_WQKV  = 0;                      // [3072][2048] bf16
static constexpr long OFF_WO    = 12582912;               // [2048][2048] bf16
static constexpr long OFF_GUW   = 20971520;               // [8][2816][2048] bf16
static constexpr long OFF_DW    = 113246208;              // [8][2048][1408] bf16
static constexpr long ARENA     = 159383552;
static constexpr long OFF_XBF   = ARENA;                  // [4096][2048] bf16 ; later vt [8][128][2048] bf16
static constexpr long OFF_QKV   = ARENA + 16777216;       // [4096][3072] bf16
static constexpr long OFF_ATT   = ARENA + 41943040;       // [4096][2048] bf16
static constexpr long OFF_GURAW = ARENA;                  // [8192][2816] bf16 (aliases x/qkv/att later)
static constexpr long OFF_H2    = 218103808;              // [4096][2048] f32
static constexpr long OFF_GU    = 218103808;              // [8192][1408] bf16 (aliases h2 later)
static constexpr long OFF_X2    = 251658240;              // [4096][2048] bf16
static constexpr long OFF_CNT   = 268435456;
static constexpr long OFF_OFFS  = 268435488;
static constexpr long OFF_LIST  = 268435520;
static constexpr long OFF_WL    = 268566592;

extern "C" void kernel_launch(void* const* d_in, const int* in_sizes, int n_in,
                              void* d_out, int out_size, void* d_ws, size_t ws_size,
                              hipStream_t stream) {
  const float* hs   = (const float*)d_in[0];
  const float* cosb = (const float*)d_in[1];
  const float* sinb = (const float*)d_in[2];
  const float* wq   = (const float*)d_in[3];
  const float* wk   = (const float*)d_in[4];
  const float* wv   = (const float*)d_in[5];
  const float* wo   = (const float*)d_in[6];
  const float* ln1  = (const float*)d_in[7];
  const float* ln2  = (const float*)d_in[8];
  const float* rw   = (const float*)d_in[9];
  const float* gw   = (const float*)d_in[10];
  const float* uw   = (const float*)d_in[11];
  const float* dw   = (const float*)d_in[12];
  float* out = (float*)d_out;
  char* ws = (char*)d_ws;

  u16* wqkv_bt = (u16*)(ws + OFF_WQKV);
  u16* wo_bt   = (u16*)(ws + OFF_WO);
  u16* guw_bt  = (u16*)(ws + OFF_GUW);
  u16* dw_bt   = (u16*)(ws + OFF_DW);
  u16* x_bf    = (u16*)(ws + OFF_XBF);
  u16* qkv_bf  = (u16*)(ws + OFF_QKV);
  u16* att_bf  = (u16*)(ws + OFF_ATT);
  u16* guraw   = (u16*)(ws + OFF_GURAW);
  float* h2    = (float*)(ws + OFF_H2);
  u16* gu      = (u16*)(ws + OFF_GU);
  u16* x2_bf   = (u16*)(ws + OFF_X2);
  u16* vt      = (u16*)(ws + OFF_XBF);   // aliases x_bf (dead after QKV GEMM)
  int* counts  = (int*)(ws + OFF_CNT);
  int* offs    = (int*)(ws + OFF_OFFS);
  int* lists   = (int*)(ws + OFF_LIST);
  float* wlists= (float*)(ws + OFF_WL);

  dim3 tb(32,8);
  tconv<<<dim3(64,64,1),tb,0,stream>>>(wq, wqkv_bt,                2048,2048,2048, 0,0);
  tconv<<<dim3(16,64,1),tb,0,stream>>>(wk, wqkv_bt + 2048L*2048,   2048, 512,2048, 0,0);
  tconv<<<dim3(16,64,1),tb,0,stream>>>(wv, wqkv_bt + 2560L*2048,   2048, 512,2048, 0,0);
  tconv<<<dim3(64,64,1),tb,0,stream>>>(wo, wo_bt,                  2048,2048,2048, 0,0);
  tconv<<<dim3(44,64,8),tb,0,stream>>>(gw, guw_bt,                 2048,1408,2048, 2048L*1408, 2816L*2048);
  tconv<<<dim3(44,64,8),tb,0,stream>>>(uw, guw_bt + 1408L*2048,    2048,1408,2048, 2048L*1408, 2816L*2048);
  tconv<<<dim3(64,44,8),tb,0,stream>>>(dw, dw_bt,                  1408,2048,1408, 1408L*2048, 2048L*1408);

  rmsnorm_k<<<TT,256,0,stream>>>(hs, ln1, x_bf);

  gemm_bt<0,false,false><<<dim3(24,32,1),256,0,stream>>>(x_bf, wqkv_bt, 2048, 4096,
      nullptr,nullptr,nullptr,nullptr, 0, qkv_bf, 3072, nullptr,nullptr,nullptr);

  rope_k<<<TT,256,0,stream>>>(qkv_bf, cosb, sinb);

  // v transpose (x_bf dead now): vt[(b*4+g)][d][s]
  vtrans<<<dim3(64,4,8),tb,0,stream>>>(qkv_bf, vt);

  attn_k<<<dim3(16,16,2),256,0,stream>>>(qkv_bf, vt, att_bf);

  gemm_bt<1,false,false><<<dim3(16,32,1),256,0,stream>>>(att_bf, wo_bt, 2048, 4096,
      nullptr,nullptr,nullptr,nullptr, 0, nullptr, 2048, h2, out, hs);

  rmsnorm_k<<<TT,256,0,stream>>>(h2, ln2, x2_bf);
  zero8<<<1,64,0,stream>>>(counts);
  router_k<<<TT,256,0,stream>>>(h2, ln2, rw, counts, lists, wlists);
  prefix8<<<1,64,0,stream>>>(counts, offs);

  gemm_bt<0,true,true><<<dim3(22,32,8),256,0,stream>>>(x2_bf, guw_bt, 2048, 0,
      counts, offs, lists, wlists, 2816L*2048, guraw, 2816, nullptr,nullptr,nullptr);

  silu_k<<<8192,256,0,stream>>>(guraw, gu);

  gemm_bt<2,false,true><<<dim3(16,32,8),256,0,stream>>>(gu, dw_bt, 1408, 0,
      counts, offs, lists, wlists, 2048L*1408, nullptr, 2048, out, nullptr, nullptr);

  (void)in_sizes; (void)n_in; (void)out_size; (void)ws_size;
}

// Round 3
// 1131.942 us; speedup vs baseline: 2.9557x; 1.0200x over previous
//
#include <hip/hip_runtime.h>

typedef unsigned short u16;
typedef u16 u16x8 __attribute__((ext_vector_type(8)));
typedef short s16x8 __attribute__((ext_vector_type(8)));
typedef float f32x4 __attribute__((ext_vector_type(4)));

#define TT 4096   // B*S tokens
#define HH 2048   // hidden

__device__ __forceinline__ float bf2f(u16 u){ union{unsigned int i; float f;} v; v.i = ((unsigned int)u)<<16; return v.f; }
__device__ __forceinline__ u16 f2bf(float f){ union{float f; unsigned int i;} v; v.f = f; unsigned int r = v.i + 0x7fffu + ((v.i>>16)&1u); return (u16)(r>>16); }

__device__ __forceinline__ void gl_lds16(const u16* g, u16* l){
  __builtin_amdgcn_global_load_lds((const __attribute__((address_space(1))) unsigned int*)g,
                                   (__attribute__((address_space(3))) unsigned int*)l, 16, 0, 0);
}

// ---------------- transpose + fp32->bf16 convert: in [R][C] f32 -> out [C][ldo] bf16 (out[c*ldo+r]) ----------
__global__ __launch_bounds__(256) void tconv(const float* __restrict__ in, u16* __restrict__ out,
    int R, int C, int ldo, long inB, long outB){
  __shared__ float t[32][33];
  const float* inp = in + (long)blockIdx.z * inB;
  u16* outp = out + (long)blockIdx.z * outB;
  int c0 = blockIdx.x*32, r0 = blockIdx.y*32;
  int tx = threadIdx.x, ty = threadIdx.y;  // 32 x 8
  #pragma unroll
  for (int j=0;j<4;j++){
    int r = r0 + ty + j*8;
    t[ty+j*8][tx] = inp[(long)r*C + (c0+tx)];
  }
  __syncthreads();
  #pragma unroll
  for (int j=0;j<4;j++){
    int c = c0 + ty + j*8;
    outp[(long)c*ldo + (r0+tx)] = f2bf(t[tx][ty+j*8]);
  }
}

// ---------------- bf16 transpose of V slice: qkv[t][2560+g*128+d] -> vt[(b*4+g)][d][s] ----------------
__global__ __launch_bounds__(256) void vtrans(const u16* __restrict__ qkv, u16* __restrict__ vt){
  __shared__ u16 t[32][34];
  int bg = blockIdx.z; int b = bg>>2, g = bg&3;
  int s0 = blockIdx.x*32, d0 = blockIdx.y*32;
  int tx = threadIdx.x, ty = threadIdx.y;  // 32 x 8
  #pragma unroll
  for (int j=0;j<4;j++){
    t[ty+j*8][tx] = qkv[(long)(b*2048 + s0+ty+j*8)*3072 + 2560 + g*128 + d0+tx];
  }
  __syncthreads();
  #pragma unroll
  for (int j=0;j<4;j++){
    vt[((long)bg*128 + d0+ty+j*8)*2048 + s0+tx] = t[tx][ty+j*8];
  }
}

// ---------------- RMSNorm (fp32 in, bf16 out), one block per token ----------------
__global__ __launch_bounds__(256) void rmsnorm_k(const float* __restrict__ in, const float* __restrict__ w,
                                                 u16* __restrict__ out){
  long t = blockIdx.x;
  const float* row = in + t*HH;
  int tid = threadIdx.x;
  float x[8]; float ss = 0.f;
  #pragma unroll
  for (int i=0;i<8;i++){ x[i] = row[tid + i*256]; ss += x[i]*x[i]; }
  #pragma unroll
  for (int o=1;o<64;o<<=1) ss += __shfl_xor(ss, o, 64);
  __shared__ float sw[4];
  if ((tid&63)==0) sw[tid>>6] = ss;
  __syncthreads();
  ss = sw[0]+sw[1]+sw[2]+sw[3];
  float sc = rsqrtf(ss*(1.f/HH) + 1e-6f);
  #pragma unroll
  for (int i=0;i<8;i++){ int idx = tid+i*256; out[t*HH+idx] = f2bf(x[i]*sc*w[idx]); }
}

// ---------------- generic bf16 MFMA GEMM: C[M,N] = A[M,K] @ B^T  (B given as [N][K] bf16) ----------------
// 128x128 tile, BK=32, global_load_lds(16B) staging into XOR-swizzled unpadded LDS.
template<int EPI, bool GATHER, bool GROUPED>
__global__ __launch_bounds__(256) void gemm_bt(
    const u16* __restrict__ A, const u16* __restrict__ B,
    int K, int M_fixed,
    const int* __restrict__ counts, const int* __restrict__ offsets,
    const int* __restrict__ lists, const float* __restrict__ wlists,
    long strideB,
    u16* __restrict__ Cbf, int ldc,
    float* __restrict__ Cf1, float* __restrict__ Cf2,
    const float* __restrict__ Resid)
{
  int e = GROUPED ? blockIdx.z : 0;
  int cnt = GROUPED ? counts[e] : M_fixed;
  int m0 = blockIdx.y * 128;
  if (m0 >= cnt) return;
  int n0 = blockIdx.x * 128;
  int base = GROUPED ? offsets[e] : 0;
  const u16* B2 = B + (long)e * strideB;

  __shared__ u16 lA[128*32];
  __shared__ u16 lB[128*32];

  int tid = threadIdx.x;
  int wave = tid>>6, lane = tid&63;
  int wm = (wave>>1)*64, wn = (wave&1)*64;
  int quad = lane>>4, l16 = lane&15;

  // DMA staging: lane covers row (lane>>2), swizzled k-chunk (lane&3)^((lane>>3)&3)
  int rloc = lane>>2;
  int koff = ((lane&3) ^ ((lane>>3)&3))*8;
  int r0a = m0 + wave*16 + rloc;
  int r1a = r0a + 64;
  if (r0a >= cnt) r0a = cnt-1;
  if (r1a >= cnt) r1a = cnt-1;
  long ga0, ga1;
  if constexpr (GATHER){ ga0 = (long)lists[e*4096 + r0a]*K; ga1 = (long)lists[e*4096 + r1a]*K; }
  else if constexpr (GROUPED){ ga0 = (long)(base + r0a)*K; ga1 = (long)(base + r1a)*K; }
  else { ga0 = (long)r0a*K; ga1 = (long)r1a*K; }
  ga0 += koff; ga1 += koff;
  long gb0 = (long)(n0 + wave*16 + rloc)*K + koff;
  long gb1 = gb0 + 64L*K;
  u16* lA0 = lA + wave*16*32; u16* lA1 = lA0 + 64*32;
  u16* lB0 = lB + wave*16*32; u16* lB1 = lB0 + 64*32;

  // fragment read offsets: element (row,kc) at row*32 + (kc^((row>>1)&3))*8 ; (row>>1)&3 == (l16>>1)&3
  int sw8 = (quad ^ ((l16>>1)&3))*8;
  int aoff = (wm + l16)*32 + sw8;
  int boff = (wn + l16)*32 + sw8;

  f32x4 zero = {0.f,0.f,0.f,0.f};
  f32x4 acc[4][4];
  #pragma unroll
  for (int i=0;i<4;i++)
    #pragma unroll
    for (int j=0;j<4;j++) acc[i][j] = zero;

  for (int kt=0; kt<K; kt+=32){
    gl_lds16(A  + ga0 + kt, lA0);
    gl_lds16(A  + ga1 + kt, lA1);
    gl_lds16(B2 + gb0 + kt, lB0);
    gl_lds16(B2 + gb1 + kt, lB1);
    __syncthreads();
    s16x8 af[4], bfr[4];
    #pragma unroll
    for (int i=0;i<4;i++){
      af[i]  = *(const s16x8*)(&lA[aoff + i*512]);
      bfr[i] = *(const s16x8*)(&lB[boff + i*512]);
    }
    #pragma unroll
    for (int i=0;i<4;i++)
      #pragma unroll
      for (int j=0;j<4;j++)
        acc[i][j] = __builtin_amdgcn_mfma_f32_16x16x32_bf16(af[i], bfr[j], acc[i][j], 0,0,0);
    __syncthreads();
  }

  #pragma unroll
  for (int i=0;i<4;i++){
    #pragma unroll
    for (int j=0;j<4;j++){
      #pragma unroll
      for (int rr=0; rr<4; rr++){
        int row = m0 + wm + i*16 + quad*4 + rr;
        int col = n0 + wn + j*16 + l16;
        float v = acc[i][j][rr];
        if constexpr (EPI==0){
          if (row < cnt) Cbf[(long)(base+row)*ldc + col] = f2bf(v);
        } else if constexpr (EPI==1){
          long idx = (long)row*ldc + col;
          float o = v + Resid[idx];
          Cf1[idx] = o; Cf2[idx] = o;
        } else {
          if (row < cnt){
            int tk = lists[e*4096 + row];
            float wgt = wlists[e*4096 + row];
            atomicAdd(&Cf1[(long)tk*ldc + col], wgt*v);
          }
        }
      }
    }
  }
}

// ---------------- RoPE in-place on q (16 heads) and k (4 heads) parts of qkv_bf [T][3072] ----------------
__global__ __launch_bounds__(256) void rope_k(u16* __restrict__ qkv, const float* __restrict__ cosb,
                                              const float* __restrict__ sinb){
  long t = blockIdx.x;
  for (int p = threadIdx.x; p < 1280; p += 256){
    int head = p>>6, d = p&63;
    long base = t*3072 + (head<16 ? head*128 : 2048 + (head-16)*128);
    float c1 = cosb[t*128+d],    s1 = sinb[t*128+d];
    float c2 = cosb[t*128+d+64], s2 = sinb[t*128+d+64];
    float x1 = bf2f(qkv[base+d]), x2 = bf2f(qkv[base+d+64]);
    qkv[base+d]    = f2bf(x1*c1 - x2*s1);
    qkv[base+d+64] = f2bf(x2*c2 + x1*s2);
  }
}

// ---------------- MFMA flash attention (full, non-causal), GQA 16q/4kv, D=128 ----------------
__global__ __launch_bounds__(256,2) void attn_k(const u16* __restrict__ qkv, const u16* __restrict__ vt,
                                                u16* __restrict__ out){
  __shared__ u16 lK [64*136];   // [key][d], ld=136
  __shared__ u16 lVt[128*72];   // [d][key], ld=72
  __shared__ u16 lP [4*32*72];  // per-wave [qrow][key], ld=72
  int qt = blockIdx.x, h = blockIdx.y, b = blockIdx.z;
  int g = h>>2;
  int tid = threadIdx.x, wave = tid>>6, lane = tid&63;
  int quad = lane>>4, l16 = lane&15;
  long qbase = (long)b*2048 + qt*128;
  const float c = 0.08838834764831845f * 1.4426950408889634f;  // scale * log2(e)

  s16x8 qf[2][4];
  #pragma unroll
  for (int i=0;i<2;i++){
    long tok = qbase + wave*32 + i*16 + l16;
    #pragma unroll
    for (int kk=0;kk<4;kk++)
      qf[i][kk] = *(const s16x8*)(qkv + tok*3072 + h*128 + kk*32 + quad*8);
  }

  f32x4 O[2][8];
  #pragma unroll
  for (int i=0;i<2;i++)
    #pragma unroll
    for (int f=0;f<8;f++) O[i][f] = (f32x4){0.f,0.f,0.f,0.f};
  float mS[2][4], lS[2][4];
  #pragma unroll
  for (int i=0;i<2;i++)
    #pragma unroll
    for (int rr=0;rr<4;rr++){ mS[i][rr] = -1e30f; lS[i][rr] = 0.f; }

  const u16* kbase  = qkv + (long)b*2048*3072 + 2048 + g*128;
  const u16* vtbase = vt + ((long)(b*4+g))*128*2048;
  int koct = tid&15, krow = tid>>4;
  int voct = tid&7,  vrow = tid>>3;
  u16* lPw = lP + wave*32*72;

  for (int kt=0; kt<2048; kt+=64){
    __syncthreads();
    #pragma unroll
    for (int j2=0;j2<4;j2++){
      int r = krow + j2*16;
      *(u16x8*)(lK + r*136 + koct*8) = *(const u16x8*)(kbase + (long)(kt+r)*3072 + koct*8);
    }
    #pragma unroll
    for (int j2=0;j2<4;j2++){
      int d = vrow + j2*32;
      *(u16x8*)(lVt + d*72 + voct*8) = *(const u16x8*)(vtbase + (long)d*2048 + kt + voct*8);
    }
    __syncthreads();

    f32x4 S[2][4];
    #pragma unroll
    for (int i=0;i<2;i++)
      #pragma unroll
      for (int j=0;j<4;j++) S[i][j] = (f32x4){0.f,0.f,0.f,0.f};
    #pragma unroll
    for (int kk=0;kk<4;kk++){
      s16x8 bk[4];
      #pragma unroll
      for (int j=0;j<4;j++)
        bk[j] = *(const s16x8*)(lK + (j*16+l16)*136 + kk*32 + quad*8);
      #pragma unroll
      for (int i=0;i<2;i++)
        #pragma unroll
        for (int j=0;j<4;j++)
          S[i][j] = __builtin_amdgcn_mfma_f32_16x16x32_bf16(qf[i][kk], bk[j], S[i][j], 0,0,0);
    }

    #pragma unroll
    for (int i=0;i<2;i++){
      float al[4];
      #pragma unroll
      for (int rr=0;rr<4;rr++){
        float v = fmaxf(fmaxf(S[i][0][rr],S[i][1][rr]), fmaxf(S[i][2][rr],S[i][3][rr]));
        v = fmaxf(v, __shfl_xor(v,1,64));
        v = fmaxf(v, __shfl_xor(v,2,64));
        v = fmaxf(v, __shfl_xor(v,4,64));
        v = fmaxf(v, __shfl_xor(v,8,64));
        float mn = fmaxf(v, mS[i][rr]);
        al[rr] = exp2f((mS[i][rr]-mn)*c);
        mS[i][rr] = mn;
        float rs = 0.f;
        #pragma unroll
        for (int j=0;j<4;j++){
          float p = exp2f((S[i][j][rr]-mn)*c);
          S[i][j][rr] = p; rs += p;
        }
        rs += __shfl_xor(rs,1,64);
        rs += __shfl_xor(rs,2,64);
        rs += __shfl_xor(rs,4,64);
        rs += __shfl_xor(rs,8,64);
        lS[i][rr] = lS[i][rr]*al[rr] + rs;
      }
      #pragma unroll
      for (int j=0;j<4;j++)
        #pragma unroll
        for (int rr=0;rr<4;rr++)
          lPw[(i*16 + quad*4 + rr)*72 + j*16 + l16] = f2bf(S[i][j][rr]);
      #pragma unroll
      for (int f=0;f<8;f++)
        #pragma unroll
        for (int rr=0;rr<4;rr++) O[i][f][rr] *= al[rr];
    }

    #pragma unroll
    for (int kk=0;kk<2;kk++){
      s16x8 ap[2];
      #pragma unroll
      for (int i=0;i<2;i++)
        ap[i] = *(const s16x8*)(lPw + (i*16+l16)*72 + kk*32 + quad*8);
      #pragma unroll
      for (int f=0;f<8;f++){
        s16x8 bv = *(const s16x8*)(lVt + (f*16+l16)*72 + kk*32 + quad*8);
        O[0][f] = __builtin_amdgcn_mfma_f32_16x16x32_bf16(ap[0], bv, O[0][f], 0,0,0);
        O[1][f] = __builtin_amdgcn_mfma_f32_16x16x32_bf16(ap[1], bv, O[1][f], 0,0,0);
      }
    }
  }

  #pragma unroll
  for (int i=0;i<2;i++){
    float inv[4];
    #pragma unroll
    for (int rr=0;rr<4;rr++) inv[rr] = 1.f/lS[i][rr];
    #pragma unroll
    for (int f=0;f<8;f++)
      #pragma unroll
      for (int rr=0;rr<4;rr++){
        long tok = qbase + wave*32 + i*16 + quad*4 + rr;
        out[tok*2048 + h*128 + f*16 + l16] = f2bf(O[i][f][rr]*inv[rr]);
      }
  }
}

// ---------------- router: fused rmsnorm + logits(fp32) + softmax + top2 + routing lists ----------------
__global__ __launch_bounds__(256) void router_k(const float* __restrict__ h2, const float* __restrict__ w2,
    const float* __restrict__ rw, int* counts, int* lists, float* wlists){
  long t = blockIdx.x;
  const float* row = h2 + t*HH;
  int tid = threadIdx.x;
  float x[8]; float ss = 0.f;
  #pragma unroll
  for (int i=0;i<8;i++){ int idx = tid + i*256; x[i]=row[idx]; ss += x[i]*x[i]; }
  #pragma unroll
  for (int o=1;o<64;o<<=1) ss += __shfl_xor(ss,o,64);
  __shared__ float ssw[4];
  int wave = tid>>6, lane = tid&63;
  if (lane==0) ssw[wave]=ss;
  __syncthreads();
  ss = ssw[0]+ssw[1]+ssw[2]+ssw[3];
  float sc = rsqrtf(ss*(1.f/HH) + 1e-6f);
  float part[8] = {0,0,0,0,0,0,0,0};
  #pragma unroll
  for (int i=0;i<8;i++){
    int idx = tid + i*256;
    float xn = x[i]*sc*w2[idx];
    const float* r8 = rw + (long)idx*8;
    #pragma unroll
    for (int e2=0;e2<8;e2++) part[e2] += xn*r8[e2];
  }
  #pragma unroll
  for (int e2=0;e2<8;e2++)
    #pragma unroll
    for (int o=1;o<64;o<<=1) part[e2] += __shfl_xor(part[e2],o,64);
  __shared__ float pw[4][8];
  if (lane==0){
    #pragma unroll
    for (int e2=0;e2<8;e2++) pw[wave][e2]=part[e2];
  }
  __syncthreads();
  if (tid==0){
    float lg[8];
    #pragma unroll
    for (int e2=0;e2<8;e2++) lg[e2]=pw[0][e2]+pw[1][e2]+pw[2][e2]+pw[3][e2];
    float mx = lg[0];
    #pragma unroll
    for (int e2=1;e2<8;e2++) mx = fmaxf(mx, lg[e2]);
    float pz[8];
    #pragma unroll
    for (int e2=0;e2<8;e2++) pz[e2] = __expf(lg[e2]-mx);
    int i1 = 0;
    #pragma unroll
    for (int e2=1;e2<8;e2++) if (pz[e2] > pz[i1]) i1 = e2;
    int i2 = (i1==0) ? 1 : 0;
    #pragma unroll
    for (int e2=0;e2<8;e2++) if (e2!=i1 && pz[e2] > pz[i2]) i2 = e2;
    float v1 = pz[i1], v2 = pz[i2];
    float inv = 1.f/(v1+v2);
    int p1 = atomicAdd(&counts[i1],1);
    lists[i1*4096+p1] = (int)t; wlists[i1*4096+p1] = v1*inv;
    int p2 = atomicAdd(&counts[i2],1);
    lists[i2*4096+p2] = (int)t; wlists[i2*4096+p2] = v2*inv;
  }
}

__global__ void zero8(int* p){ if (threadIdx.x < 8) p[threadIdx.x] = 0; }
__global__ void prefix8(const int* __restrict__ counts, int* __restrict__ offs){
  if (threadIdx.x==0){ int o=0; for (int e=0;e<8;e++){ offs[e]=o; o+=counts[e]; } }
}

// ---------------- silu(g)*u elementwise: guraw [8192][2816] -> gu [8192][1408] ----------------
__global__ __launch_bounds__(256) void silu_k(const u16* __restrict__ graw, u16* __restrict__ gu){
  long row = blockIdx.x;
  const u16* gr = graw + row*2816;
  u16* o = gu + row*1408;
  for (int i = threadIdx.x; i < 1408; i += 256){
    float g = bf2f(gr[i]);
    float u = bf2f(gr[1408+i]);
    float s = g / (1.f + __expf(-g));
    o[i] = f2bf(s*u);
  }
}

// ---------------- workspace layout (bytes) ----------------
static constexpr long OFF_WQKV  = 0;                      // [3072][2048] bf16
static constexpr long OFF_WO    = 12582912;               // [2048][2048] bf16
static constexpr long OFF_GUW   = 20971520;               // [8][2816][2048] bf16
static constexpr long OFF_DW    = 113246208;              // [8][2048][1408] bf16
static constexpr long ARENA     = 159383552;
static constexpr long OFF_XBF   = ARENA;                  // [4096][2048] bf16 ; later vt [8][128][2048] bf16
static constexpr long OFF_QKV   = ARENA + 16777216;       // [4096][3072] bf16
static constexpr long OFF_ATT   = ARENA + 41943040;       // [4096][2048] bf16
static constexpr long OFF_GURAW = ARENA;                  // [8192][2816] bf16 (aliases x/qkv/att later)
static constexpr long OFF_H2    = 218103808;              // [4096][2048] f32
static constexpr long OFF_GU    = 218103808;              // [8192][1408] bf16 (aliases h2 later)
static constexpr long OFF_X2    = 251658240;              // [4096][2048] bf16
static constexpr long OFF_CNT   = 268435456;
static constexpr long OFF_OFFS  = 268435488;
static constexpr long OFF_LIST  = 268435520;
static constexpr long OFF_WL    = 268566592;

extern "C" void kernel_launch(void* const* d_in, const int* in_sizes, int n_in,
                              void* d_out, int out_size, void* d_ws, size_t ws_size,
                              hipStream_t stream) {
  const float* hs   = (const float*)d_in[0];
  const float* cosb = (const float*)d_in[1];
  const float* sinb = (const float*)d_in[2];
  const float* wq   = (const float*)d_in[3];
  const float* wk   = (const float*)d_in[4];
  const float* wv   = (const float*)d_in[5];
  const float* wo   = (const float*)d_in[6];
  const float* ln1  = (const float*)d_in[7];
  const float* ln2  = (const float*)d_in[8];
  const float* rw   = (const float*)d_in[9];
  const float* gw   = (const float*)d_in[10];
  const float* uw   = (const float*)d_in[11];
  const float* dw   = (const float*)d_in[12];
  float* out = (float*)d_out;
  char* ws = (char*)d_ws;

  u16* wqkv_bt = (u16*)(ws + OFF_WQKV);
  u16* wo_bt   = (u16*)(ws + OFF_WO);
  u16* guw_bt  = (u16*)(ws + OFF_GUW);
  u16* dw_bt   = (u16*)(ws + OFF_DW);
  u16* x_bf    = (u16*)(ws + OFF_XBF);
  u16* qkv_bf  = (u16*)(ws + OFF_QKV);
  u16* att_bf  = (u16*)(ws + OFF_ATT);
  u16* guraw   = (u16*)(ws + OFF_GURAW);
  float* h2    = (float*)(ws + OFF_H2);
  u16* gu      = (u16*)(ws + OFF_GU);
  u16* x2_bf   = (u16*)(ws + OFF_X2);
  u16* vt      = (u16*)(ws + OFF_XBF);   // aliases x_bf (dead after QKV GEMM)
  int* counts  = (int*)(ws + OFF_CNT);
  int* offs    = (int*)(ws + OFF_OFFS);
  int* lists   = (int*)(ws + OFF_LIST);
  float* wlists= (float*)(ws + OFF_WL);

  dim3 tb(32,8);
  tconv<<<dim3(64,64,1),tb,0,stream>>>(wq, wqkv_bt,                2048,2048,2048, 0,0);
  tconv<<<dim3(16,64,1),tb,0,stream>>>(wk, wqkv_bt + 2048L*2048,   2048, 512,2048, 0,0);
  tconv<<<dim3(16,64,1),tb,0,stream>>>(wv, wqkv_bt + 2560L*2048,   2048, 512,2048, 0,0);
  tconv<<<dim3(64,64,1),tb,0,stream>>>(wo, wo_bt,                  2048,2048,2048, 0,0);
  tconv<<<dim3(44,64,8),tb,0,stream>>>(gw, guw_bt,                 2048,1408,2048, 2048L*1408, 2816L*2048);
  tconv<<<dim3(44,64,8),tb,0,stream>>>(uw, guw_bt + 1408L*2048,    2048,1408,2048, 2048L*1408, 2816L*2048);
  tconv<<<dim3(64,44,8),tb,0,stream>>>(dw, dw_bt,                  1408,2048,1408, 1408L*2048, 2048L*1408);

  rmsnorm_k<<<TT,256,0,stream>>>(hs, ln1, x_bf);

  gemm_bt<0,false,false><<<dim3(24,32,1),256,0,stream>>>(x_bf, wqkv_bt, 2048, 4096,
      nullptr,nullptr,nullptr,nullptr, 0, qkv_bf, 3072, nullptr,nullptr,nullptr);

  rope_k<<<TT,256,0,stream>>>(qkv_bf, cosb, sinb);

  vtrans<<<dim3(64,4,8),tb,0,stream>>>(qkv_bf, vt);

  attn_k<<<dim3(16,16,2),256,0,stream>>>(qkv_bf, vt, att_bf);

  gemm_bt<1,false,false><<<dim3(16,32,1),256,0,stream>>>(att_bf, wo_bt, 2048, 4096,
      nullptr,nullptr,nullptr,nullptr, 0, nullptr, 2048, h2, out, hs);

  rmsnorm_k<<<TT,256,0,stream>>>(h2, ln2, x2_bf);
  zero8<<<1,64,0,stream>>>(counts);
  router_k<<<TT,256,0,stream>>>(h2, ln2, rw, counts, lists, wlists);
  prefix8<<<1,64,0,stream>>>(counts, offs);

  gemm_bt<0,true,true><<<dim3(22,32,8),256,0,stream>>>(x2_bf, guw_bt, 2048, 0,
      counts, offs, lists, wlists, 2816L*2048, guraw, 2816, nullptr,nullptr,nullptr);

  silu_k<<<8192,256,0,stream>>>(guraw, gu);

  gemm_bt<2,false,true><<<dim3(16,32,8),256,0,stream>>>(gu, dw_bt, 1408, 0,
      counts, offs, lists, wlists, 2048L*1408, nullptr, 2048, out, nullptr, nullptr);

  (void)in_sizes; (void)n_in; (void)out_size; (void)ws_size;
}